// Round 1
// baseline (218.282 us; speedup 1.0000x reference)
//
#include <hip/hip_runtime.h>
#include <cmath>

namespace {
constexpr int B_ = 2, K_ = 4, D_ = 128, L_ = 4096, N_ = 16, R_ = 8, C_ = 40;
constexpr int CHUNK = 128, NCHUNK = L_ / CHUNK;   // 32 chunks
constexpr int DT = 16, NDT = D_ / DT;             // 16-wide d tiles, 8 per D
constexpr int LPAD = CHUNK + 4;                   // 132: bank spread + 16B align
}

// ---------------------------------------------------------------------------
// K1: projections. One thread per l (64/block). Computes the 24 kv-projection
// channels (dt-rank + Bs) and 16 q-projection channels (Cs), then expands the
// dt rank to D with softplus -> delta. Writes delta (B,K,D,L), Bs/Cs (B,K,N,L).
// ---------------------------------------------------------------------------
__global__ __launch_bounds__(64) void k1_proj(
    const float* __restrict__ qx, const float* __restrict__ kv,
    const float* __restrict__ xw,   // (K, 40, D)
    const float* __restrict__ dtw,  // (K, D, R)
    const float* __restrict__ dtb,  // (K, D)
    float* __restrict__ delta, float* __restrict__ BsG, float* __restrict__ CsG)
{
    __shared__ float Wt[D_][C_];     // transposed: [d][c] so c is contiguous
    __shared__ float dtw_s[D_][R_];
    __shared__ float bias_s[D_];
    const int tid = threadIdx.x;
    int blk = blockIdx.x;
    const int LTB = L_ / 64;
    const int lt = blk % LTB; blk /= LTB;
    const int k = blk % K_; const int b = blk / K_;
    const int l = lt * 64 + tid;

    for (int i = tid; i < C_ * D_; i += 64) {
        int c = i / D_, d = i % D_;
        Wt[d][c] = xw[(k * C_ + c) * D_ + d];
    }
    for (int i = tid; i < D_ * R_; i += 64)
        dtw_s[i / R_][i % R_] = dtw[k * D_ * R_ + i];
    for (int i = tid; i < D_; i += 64) bias_s[i] = dtb[k * D_ + i];
    __syncthreads();

    float acc[C_];
    #pragma unroll
    for (int c = 0; c < C_; ++c) acc[c] = 0.f;
    const float* kvp = kv + (size_t)((b * K_ + k) * D_) * L_ + l;
    const float* qxp = qx + (size_t)((b * K_ + k) * D_) * L_ + l;
    for (int d = 0; d < D_; ++d) {
        float v = kvp[(size_t)d * L_];
        float q = qxp[(size_t)d * L_];
        #pragma unroll
        for (int c = 0; c < R_ + N_; ++c) acc[c] = fmaf(v, Wt[d][c], acc[c]);
        #pragma unroll
        for (int c = R_ + N_; c < C_; ++c) acc[c] = fmaf(q, Wt[d][c], acc[c]);
    }
    const size_t base_nl = (size_t)(b * K_ + k) * N_ * L_ + l;
    #pragma unroll
    for (int n = 0; n < N_; ++n) {
        BsG[base_nl + (size_t)n * L_] = acc[R_ + n];
        CsG[base_nl + (size_t)n * L_] = acc[R_ + N_ + n];
    }
    const size_t base_dl = (size_t)(b * K_ + k) * D_ * L_ + l;
    for (int d = 0; d < D_; ++d) {
        float s = bias_s[d];
        #pragma unroll
        for (int r = 0; r < R_; ++r) s = fmaf(acc[r], dtw_s[d][r], s);
        float sp = (s > 20.f) ? s : log1pf(__expf(s));   // softplus
        delta[base_dl + (size_t)d * L_] = sp;
    }
}

// ---------------------------------------------------------------------------
// K2: chunk pass 1. Block = 256 threads = 16 d x 16 n, per (b,k,dtile,chunk).
// Computes h_end of the chunk with h0=0, and the chunk delta-sum per d
// (cumprod of dA collapses to exp(sum(delta)*A)).
// ---------------------------------------------------------------------------
__global__ __launch_bounds__(256) void k2_pass1(
    const float* __restrict__ kv, const float* __restrict__ delta,
    const float* __restrict__ BsG, const float* __restrict__ A_logs,
    float* __restrict__ hend,   // (B,K,NCHUNK,D,N)
    float* __restrict__ Ssum)   // (B,K,NCHUNK,D)
{
    __shared__ float dl_t[DT][LPAD];
    __shared__ float u_t[DT][LPAD];
    __shared__ float b_t[N_][LPAD];
    const int tid = threadIdx.x;
    const int n = tid & 15, dl = tid >> 4;
    int blk = blockIdx.x;
    const int chunk = blk % NCHUNK; blk /= NCHUNK;
    const int dt = blk % NDT; blk /= NDT;
    const int k = blk % K_; const int b = blk / K_;
    const int bk = b * K_ + k;
    const int d = dt * DT + dl;

    const float* dsrc = delta + ((size_t)bk * D_ + dt * DT) * L_ + chunk * CHUNK;
    const float* usrc = kv    + ((size_t)bk * D_ + dt * DT) * L_ + chunk * CHUNK;
    const float* bsrc = BsG   + (size_t)bk * N_ * L_ + chunk * CHUNK;
    for (int i = tid; i < DT * (CHUNK / 4); i += 256) {
        const int row = i >> 5, c4 = (i & 31) * 4;
        *(float4*)&dl_t[row][c4] = *(const float4*)(dsrc + (size_t)row * L_ + c4);
        *(float4*)&u_t[row][c4]  = *(const float4*)(usrc + (size_t)row * L_ + c4);
        *(float4*)&b_t[row][c4]  = *(const float4*)(bsrc + (size_t)row * L_ + c4);
    }
    __syncthreads();

    const float A2 = -__expf(A_logs[(k * D_ + d) * N_ + n]) * 1.44269504f;
    float h = 0.f, sd = 0.f;
    #pragma unroll 8
    for (int l = 0; l < CHUNK; ++l) {
        const float dlt = dl_t[dl][l];
        const float xb  = dlt * u_t[dl][l];
        const float dA  = exp2f(dlt * A2);
        h = fmaf(dA, h, xb * b_t[n][l]);
        sd += dlt;
    }
    hend[(((size_t)bk * NCHUNK + chunk) * D_ + d) * N_ + n] = h;
    if (n == 0) Ssum[((size_t)bk * NCHUNK + chunk) * D_ + d] = sd;
}

// ---------------------------------------------------------------------------
// K3: combine + chunk pass 2 + output. Rebuilds h_init for this chunk from
// all previous chunks' (h_end, Ssum), rescans the chunk, reduces y over n via
// shfl butterfly (16-lane groups == one d), writes y + u*Ds coalesced.
// ---------------------------------------------------------------------------
__global__ __launch_bounds__(256) void k3_pass2(
    const float* __restrict__ kv, const float* __restrict__ delta,
    const float* __restrict__ BsG, const float* __restrict__ CsG,
    const float* __restrict__ A_logs, const float* __restrict__ DsG,
    const float* __restrict__ hend, const float* __restrict__ Ssum,
    float* __restrict__ out)
{
    __shared__ float dl_t[DT][LPAD];
    __shared__ float u_t[DT][LPAD];
    __shared__ float b_t[N_][LPAD];
    __shared__ float c_t[N_][LPAD];
    __shared__ float y_t[DT][LPAD];
    const int tid = threadIdx.x;
    const int n = tid & 15, dl = tid >> 4;
    int blk = blockIdx.x;
    const int chunk = blk % NCHUNK; blk /= NCHUNK;
    const int dt = blk % NDT; blk /= NDT;
    const int k = blk % K_; const int b = blk / K_;
    const int bk = b * K_ + k;
    const int d = dt * DT + dl;

    const float* dsrc = delta + ((size_t)bk * D_ + dt * DT) * L_ + chunk * CHUNK;
    const float* usrc = kv    + ((size_t)bk * D_ + dt * DT) * L_ + chunk * CHUNK;
    const float* bsrc = BsG   + (size_t)bk * N_ * L_ + chunk * CHUNK;
    const float* csrc = CsG   + (size_t)bk * N_ * L_ + chunk * CHUNK;
    for (int i = tid; i < DT * (CHUNK / 4); i += 256) {
        const int row = i >> 5, c4 = (i & 31) * 4;
        *(float4*)&dl_t[row][c4] = *(const float4*)(dsrc + (size_t)row * L_ + c4);
        *(float4*)&u_t[row][c4]  = *(const float4*)(usrc + (size_t)row * L_ + c4);
        *(float4*)&b_t[row][c4]  = *(const float4*)(bsrc + (size_t)row * L_ + c4);
        *(float4*)&c_t[row][c4]  = *(const float4*)(csrc + (size_t)row * L_ + c4);
    }
    __syncthreads();

    const float A2 = -__expf(A_logs[(k * D_ + d) * N_ + n]) * 1.44269504f;

    // Combine: fold previous chunks into h_init. P(cc) = exp(Ssum(cc)*A).
    float h = 0.f;
    for (int cc = 0; cc < chunk; ++cc) {
        const float S = Ssum[((size_t)bk * NCHUNK + cc) * D_ + d];
        const float P = exp2f(S * A2);
        h = fmaf(P, h, hend[(((size_t)bk * NCHUNK + cc) * D_ + d) * N_ + n]);
    }

    #pragma unroll 4
    for (int l = 0; l < CHUNK; ++l) {
        const float dlt = dl_t[dl][l];
        const float xb  = dlt * u_t[dl][l];
        const float dA  = exp2f(dlt * A2);
        h = fmaf(dA, h, xb * b_t[n][l]);
        float p = h * c_t[n][l];
        p += __shfl_xor(p, 1, 16);
        p += __shfl_xor(p, 2, 16);
        p += __shfl_xor(p, 4, 16);
        p += __shfl_xor(p, 8, 16);
        if (n == 0) y_t[dl][l] = p;
    }
    __syncthreads();

    const float* ds_base = DsG + k * D_ + dt * DT;
    for (int i = tid; i < DT * (CHUNK / 4); i += 256) {
        const int row = i >> 5, c4 = (i & 31) * 4;
        const float Dv = ds_base[row];
        float4 y = *(const float4*)&y_t[row][c4];
        float4 u = *(const float4*)&u_t[row][c4];
        float4 o;
        o.x = fmaf(u.x, Dv, y.x); o.y = fmaf(u.y, Dv, y.y);
        o.z = fmaf(u.z, Dv, y.z); o.w = fmaf(u.w, Dv, y.w);
        *(float4*)(out + ((size_t)bk * D_ + dt * DT + row) * L_ + chunk * CHUNK + c4) = o;
    }
}

extern "C" void kernel_launch(void* const* d_in, const int* in_sizes, int n_in,
                              void* d_out, int out_size, void* d_ws, size_t ws_size,
                              hipStream_t stream)
{
    const float* qx  = (const float*)d_in[0];   // q_x  (B,K,D,L)
    const float* kv  = (const float*)d_in[1];   // kv_x (B,K,D,L)
    const float* xw  = (const float*)d_in[2];   // x_proj_weight (K,40,D)
    const float* dtw = (const float*)d_in[3];   // dt_projs_weight (K,D,R)
    const float* dtb = (const float*)d_in[4];   // dt_projs_bias (K,D)
    const float* alg = (const float*)d_in[5];   // A_logs (K*D,N)
    const float* Ds  = (const float*)d_in[6];   // Ds (K*D,)
    float* out = (float*)d_out;

    const size_t sz_delta = (size_t)B_ * K_ * D_ * L_;        // 4,194,304
    const size_t sz_bc    = (size_t)B_ * K_ * N_ * L_;        //   524,288
    const size_t sz_hend  = (size_t)B_ * K_ * NCHUNK * D_ * N_; // 524,288
    const size_t sz_ss    = (size_t)B_ * K_ * NCHUNK * D_;    //    32,768
    const size_t need = (sz_delta + 2 * sz_bc + sz_hend + sz_ss) * sizeof(float);
    if (ws_size < need) return;   // ~23 MB required

    float* ws    = (float*)d_ws;
    float* delta = ws;
    float* Bs    = delta + sz_delta;
    float* Cs    = Bs + sz_bc;
    float* hend  = Cs + sz_bc;
    float* Ssm   = hend + sz_hend;

    k1_proj<<<B_ * K_ * (L_ / 64), 64, 0, stream>>>(qx, kv, xw, dtw, dtb, delta, Bs, Cs);
    k2_pass1<<<B_ * K_ * NDT * NCHUNK, 256, 0, stream>>>(kv, delta, Bs, alg, hend, Ssm);
    k3_pass2<<<B_ * K_ * NDT * NCHUNK, 256, 0, stream>>>(kv, delta, Bs, Cs, alg, Ds, hend, Ssm, out);
}

// Round 2
// 111.911 us; speedup vs baseline: 1.9505x; 1.9505x over previous
//
#include <hip/hip_runtime.h>
#include <cmath>

namespace {
constexpr int B_ = 2, K_ = 4, D_ = 128, L_ = 4096, N_ = 16, R_ = 8, C_ = 40;
constexpr float LOG2E = 1.44269504f;
}

#if __has_builtin(__builtin_amdgcn_exp2f)
#define FEXP2(x) __builtin_amdgcn_exp2f(x)
#else
#define FEXP2(x) exp2f(x)
#endif

// ---------------------------------------------------------------------------
// K1: projections. Block = 128 (2 waves, 64 l's). Wave0: kv -> dt-rank(8)+Bs(16)
// channels, then delta = softplus(dt-rank @ dtw + bias) for all 128 d, staged
// to LDS and flushed as l-major deltaT (B,K,L,D). Wave1: q -> Cs(16) channels,
// written l-major CT (B,K,L,N). Wave0 also writes BT (B,K,L,N).
// ---------------------------------------------------------------------------
__global__ __launch_bounds__(128, 2) void k1_proj(
    const float* __restrict__ qx, const float* __restrict__ kv,
    const float* __restrict__ xw,   // (K, 40, D)
    const float* __restrict__ dtw,  // (K, D, R)
    const float* __restrict__ dtb,  // (K, D)
    float* __restrict__ dT,         // (B,K,L,D)
    float* __restrict__ BT,         // (B,K,L,N)
    float* __restrict__ CT)         // (B,K,L,N)
{
    __shared__ float Wt[D_ * C_];        // [d][c]
    __shared__ float dtw_s[D_ * R_];     // [d][r]
    __shared__ float bias_s[D_];
    __shared__ float dT_s[64 * 132];     // [l_local][d], stride 132 (16B-aligned rows)

    const int tid = threadIdx.x;
    const int w = tid >> 6, t = tid & 63;
    int blk = blockIdx.x;
    const int LTB = L_ / 64;
    const int lt = blk % LTB; blk /= LTB;
    const int k = blk % K_; const int b = blk / K_;
    const int bk = b * K_ + k;
    const int l = lt * 64 + t;

    for (int i = tid; i < C_ * D_; i += 128) {
        int c = i >> 7, d = i & 127;
        Wt[d * C_ + c] = xw[(k * C_ + c) * D_ + d];
    }
    for (int i = tid; i < D_ * R_; i += 128) dtw_s[i] = dtw[k * D_ * R_ + i];
    for (int i = tid; i < D_; i += 128) bias_s[i] = dtb[k * D_ + i];
    __syncthreads();

    if (w == 0) {
        // kv path: channels 0..23 (dt-rank + Bs)
        float acc[24];
        #pragma unroll
        for (int c = 0; c < 24; ++c) acc[c] = 0.f;
        const float* kvp = kv + ((size_t)bk * D_) * L_ + l;
        #pragma unroll 4
        for (int d = 0; d < D_; ++d) {
            const float v = kvp[(size_t)d * L_];
            const float* wr = &Wt[d * C_];
            #pragma unroll
            for (int c = 0; c < 24; ++c) acc[c] = fmaf(v, wr[c], acc[c]);
        }
        // Bs -> BT (l-major)
        float* bt = BT + ((size_t)bk * L_ + l) * N_;
        #pragma unroll
        for (int j = 0; j < 4; ++j) {
            float4 o; o.x = acc[8 + 4*j]; o.y = acc[9 + 4*j]; o.z = acc[10 + 4*j]; o.w = acc[11 + 4*j];
            *(float4*)(bt + 4*j) = o;
        }
        // delta for all 128 d, packed 4 at a time into LDS transpose tile
        for (int d0 = 0; d0 < D_; d0 += 4) {
            float4 dv;
            float* dvp = (float*)&dv;
            #pragma unroll
            for (int dd = 0; dd < 4; ++dd) {
                const int d = d0 + dd;
                float s = bias_s[d];
                const float* dr = &dtw_s[d * R_];
                #pragma unroll
                for (int r = 0; r < R_; ++r) s = fmaf(acc[r], dr[r], s);
                dvp[dd] = (s > 15.f) ? s : __logf(1.f + __expf(s));
            }
            *(float4*)&dT_s[t * 132 + d0] = dv;
        }
    } else {
        // q path: channels 24..39 (Cs)
        float acc[16];
        #pragma unroll
        for (int c = 0; c < 16; ++c) acc[c] = 0.f;
        const float* qp = qx + ((size_t)bk * D_) * L_ + l;
        #pragma unroll 4
        for (int d = 0; d < D_; ++d) {
            const float v = qp[(size_t)d * L_];
            const float* wr = &Wt[d * C_ + 24];
            #pragma unroll
            for (int c = 0; c < 16; ++c) acc[c] = fmaf(v, wr[c], acc[c]);
        }
        float* ct = CT + ((size_t)bk * L_ + l) * N_;
        #pragma unroll
        for (int j = 0; j < 4; ++j) {
            float4 o; o.x = acc[4*j]; o.y = acc[1 + 4*j]; o.z = acc[2 + 4*j]; o.w = acc[3 + 4*j];
            *(float4*)(ct + 4*j) = o;
        }
    }
    __syncthreads();
    // flush deltaT tile: 64 l x 128 d = 2048 float4, coalesced global writes
    for (int f = tid; f < 2048; f += 128) {
        const int ll = f >> 5, j4 = (f & 31) * 4;
        float4 v = *(const float4*)&dT_s[ll * 132 + j4];
        *(float4*)(dT + ((size_t)bk * L_ + lt * 64 + ll) * D_ + j4) = v;
    }
}

// ---------------------------------------------------------------------------
// K2: pass 1. Block = 128 threads (lane = d), per (b,k,chunk). All 16 n-states
// in registers. Writes h_end (h0=0) and chunk delta-sum.
// ---------------------------------------------------------------------------
template<int CHUNK>
__global__ __launch_bounds__(128, 2) void k2_pass1(
    const float* __restrict__ kv, const float* __restrict__ dT,
    const float* __restrict__ BT, const float* __restrict__ alg,
    float* __restrict__ hend,   // (B,K,NCH,D,N)
    float* __restrict__ Ssum)   // (B,K,NCH,D)
{
    constexpr int NCH = L_ / CHUNK;
    constexpr int S = CHUNK + 1;       // odd stride: (d + l) % 32 banking, 2-way free
    constexpr int J = CHUNK / 4;
    __shared__ float u_s[D_ * S];
    __shared__ float B_s[CHUNK * N_];

    const int tid = threadIdx.x;
    const int d = tid;
    int blk = blockIdx.x;
    const int ch = blk % NCH; blk /= NCH;
    const int k = blk % K_; const int b = blk / K_;
    const int bk = b * K_ + k;

    // stage u (transpose kv chunk into LDS, scalar writes -> conflict-free)
    for (int f = tid; f < D_ * J; f += 128) {
        const int d0 = f / J, j4 = (f % J) * 4;
        float4 v = *(const float4*)(kv + ((size_t)bk * D_ + d0) * L_ + ch * CHUNK + j4);
        float* p = &u_s[d0 * S + j4];
        p[0] = v.x; p[1] = v.y; p[2] = v.z; p[3] = v.w;
    }
    // stage B chunk (contiguous in BT)
    {
        const float* src = BT + ((size_t)bk * L_ + ch * CHUNK) * N_;
        for (int f = tid; f < CHUNK * 4; f += 128)
            *(float4*)&B_s[4 * f] = *(const float4*)(src + 4 * f);
    }
    __syncthreads();

    float A2[N_];
    {
        const float* ap = alg + ((size_t)k * D_ + d) * N_;
        #pragma unroll
        for (int j = 0; j < 4; ++j) {
            float4 a = *(const float4*)(ap + 4 * j);
            A2[4*j]   = -__expf(a.x) * LOG2E; A2[4*j+1] = -__expf(a.y) * LOG2E;
            A2[4*j+2] = -__expf(a.z) * LOG2E; A2[4*j+3] = -__expf(a.w) * LOG2E;
        }
    }

    float h[N_];
    #pragma unroll
    for (int n = 0; n < N_; ++n) h[n] = 0.f;
    float sd = 0.f;

    const float* drow = dT + ((size_t)bk * L_ + ch * CHUNK) * D_ + d;
    #pragma unroll 4
    for (int l = 0; l < CHUNK; ++l) {
        const float dlt = drow[(size_t)l * D_];
        const float uu  = u_s[d * S + l];
        const float xb  = dlt * uu;
        sd += dlt;
        float bv[N_];
        *(float4*)&bv[0]  = *(const float4*)&B_s[l * N_ + 0];
        *(float4*)&bv[4]  = *(const float4*)&B_s[l * N_ + 4];
        *(float4*)&bv[8]  = *(const float4*)&B_s[l * N_ + 8];
        *(float4*)&bv[12] = *(const float4*)&B_s[l * N_ + 12];
        #pragma unroll
        for (int n = 0; n < N_; ++n)
            h[n] = fmaf(FEXP2(dlt * A2[n]), h[n], xb * bv[n]);
    }

    float* hp = hend + (((size_t)bk * NCH + ch) * D_ + d) * N_;
    #pragma unroll
    for (int j = 0; j < 4; ++j) {
        float4 o; o.x = h[4*j]; o.y = h[4*j+1]; o.z = h[4*j+2]; o.w = h[4*j+3];
        *(float4*)(hp + 4 * j) = o;
    }
    Ssum[((size_t)bk * NCH + ch) * D_ + d] = sd;
}

// ---------------------------------------------------------------------------
// K2.5: serial chain over chunks. Thread per (b,k,d,n). Converts hend -> hinit
// IN PLACE: hinit[cc] = combined state of chunks < cc.
// ---------------------------------------------------------------------------
__global__ __launch_bounds__(256, 2) void k25_chain(
    const float* __restrict__ alg, const float* __restrict__ Ssum,
    float* __restrict__ hh, int NCH)
{
    const int tg = blockIdx.x * 256 + threadIdx.x;   // 16384 threads
    const int n = tg & 15;
    const int d = (tg >> 4) & 127;
    const int bk = tg >> 11;
    const int k = bk & 3;

    const float A2 = -__expf(alg[((size_t)k * D_ + d) * N_ + n]) * LOG2E;
    float h = 0.f;
    for (int cc = 0; cc < NCH; ++cc) {
        const size_t si = ((size_t)bk * NCH + cc) * D_ + d;
        const float Sv = Ssum[si];
        const float he = hh[si * N_ + n];
        hh[si * N_ + n] = h;                       // hinit for chunk cc
        h = fmaf(FEXP2(Sv * A2), h, he);
    }
}

// ---------------------------------------------------------------------------
// K3: pass 2. Same structure as K2 + C, starting from hinit; y = sum_n h*C in
// registers; y staged in LDS tile, flushed with +u*Ds coalesced.
// ---------------------------------------------------------------------------
template<int CHUNK>
__global__ __launch_bounds__(128, 2) void k3_pass2(
    const float* __restrict__ kv, const float* __restrict__ dT,
    const float* __restrict__ BT, const float* __restrict__ CT,
    const float* __restrict__ alg, const float* __restrict__ DsG,
    const float* __restrict__ hinit, float* __restrict__ out)
{
    constexpr int NCH = L_ / CHUNK;
    constexpr int S = CHUNK + 1;
    constexpr int J = CHUNK / 4;
    __shared__ float u_s[D_ * S];
    __shared__ float y_s[D_ * S];
    __shared__ float B_s[CHUNK * N_];
    __shared__ float C_s[CHUNK * N_];

    const int tid = threadIdx.x;
    const int d = tid;
    int blk = blockIdx.x;
    const int ch = blk % NCH; blk /= NCH;
    const int k = blk % K_; const int b = blk / K_;
    const int bk = b * K_ + k;

    for (int f = tid; f < D_ * J; f += 128) {
        const int d0 = f / J, j4 = (f % J) * 4;
        float4 v = *(const float4*)(kv + ((size_t)bk * D_ + d0) * L_ + ch * CHUNK + j4);
        float* p = &u_s[d0 * S + j4];
        p[0] = v.x; p[1] = v.y; p[2] = v.z; p[3] = v.w;
    }
    {
        const float* bsrc = BT + ((size_t)bk * L_ + ch * CHUNK) * N_;
        const float* csrc = CT + ((size_t)bk * L_ + ch * CHUNK) * N_;
        for (int f = tid; f < CHUNK * 4; f += 128) {
            *(float4*)&B_s[4 * f] = *(const float4*)(bsrc + 4 * f);
            *(float4*)&C_s[4 * f] = *(const float4*)(csrc + 4 * f);
        }
    }
    __syncthreads();

    float A2[N_];
    {
        const float* ap = alg + ((size_t)k * D_ + d) * N_;
        #pragma unroll
        for (int j = 0; j < 4; ++j) {
            float4 a = *(const float4*)(ap + 4 * j);
            A2[4*j]   = -__expf(a.x) * LOG2E; A2[4*j+1] = -__expf(a.y) * LOG2E;
            A2[4*j+2] = -__expf(a.z) * LOG2E; A2[4*j+3] = -__expf(a.w) * LOG2E;
        }
    }

    float h[N_];
    {
        const float* hp = hinit + (((size_t)bk * NCH + ch) * D_ + d) * N_;
        #pragma unroll
        for (int j = 0; j < 4; ++j) {
            float4 v = *(const float4*)(hp + 4 * j);
            h[4*j] = v.x; h[4*j+1] = v.y; h[4*j+2] = v.z; h[4*j+3] = v.w;
        }
    }

    const float* drow = dT + ((size_t)bk * L_ + ch * CHUNK) * D_ + d;
    #pragma unroll 4
    for (int l = 0; l < CHUNK; ++l) {
        const float dlt = drow[(size_t)l * D_];
        const float uu  = u_s[d * S + l];
        const float xb  = dlt * uu;
        float bv[N_], cv[N_];
        *(float4*)&bv[0]  = *(const float4*)&B_s[l * N_ + 0];
        *(float4*)&bv[4]  = *(const float4*)&B_s[l * N_ + 4];
        *(float4*)&bv[8]  = *(const float4*)&B_s[l * N_ + 8];
        *(float4*)&bv[12] = *(const float4*)&B_s[l * N_ + 12];
        *(float4*)&cv[0]  = *(const float4*)&C_s[l * N_ + 0];
        *(float4*)&cv[4]  = *(const float4*)&C_s[l * N_ + 4];
        *(float4*)&cv[8]  = *(const float4*)&C_s[l * N_ + 8];
        *(float4*)&cv[12] = *(const float4*)&C_s[l * N_ + 12];
        float p0 = 0.f, p1 = 0.f, p2 = 0.f, p3 = 0.f;
        #pragma unroll
        for (int n = 0; n < N_; ++n) {
            h[n] = fmaf(FEXP2(dlt * A2[n]), h[n], xb * bv[n]);
            if ((n & 3) == 0)      p0 = fmaf(h[n], cv[n], p0);
            else if ((n & 3) == 1) p1 = fmaf(h[n], cv[n], p1);
            else if ((n & 3) == 2) p2 = fmaf(h[n], cv[n], p2);
            else                   p3 = fmaf(h[n], cv[n], p3);
        }
        y_s[d * S + l] = (p0 + p1) + (p2 + p3);
    }
    __syncthreads();

    // flush: out = y + u * Ds
    for (int f = tid; f < D_ * J; f += 128) {
        const int d0 = f / J, j4 = (f % J) * 4;
        const float Dv = DsG[k * D_ + d0];
        const float* yp = &y_s[d0 * S + j4];
        const float* up = &u_s[d0 * S + j4];
        float4 o;
        o.x = fmaf(up[0], Dv, yp[0]); o.y = fmaf(up[1], Dv, yp[1]);
        o.z = fmaf(up[2], Dv, yp[2]); o.w = fmaf(up[3], Dv, yp[3]);
        *(float4*)(out + ((size_t)bk * D_ + d0) * L_ + ch * CHUNK + j4) = o;
    }
}

extern "C" void kernel_launch(void* const* d_in, const int* in_sizes, int n_in,
                              void* d_out, int out_size, void* d_ws, size_t ws_size,
                              hipStream_t stream)
{
    const float* qx  = (const float*)d_in[0];
    const float* kv  = (const float*)d_in[1];
    const float* xw  = (const float*)d_in[2];
    const float* dtw = (const float*)d_in[3];
    const float* dtb = (const float*)d_in[4];
    const float* alg = (const float*)d_in[5];
    const float* Ds  = (const float*)d_in[6];
    float* out = (float*)d_out;

    const size_t sz_dT = (size_t)B_ * K_ * L_ * D_;   // 4,194,304
    const size_t sz_bc = (size_t)B_ * K_ * L_ * N_;   //   524,288

    auto run = [&](auto chunk_tag, int NCH, float* wsf) {
        constexpr int CHUNK = decltype(chunk_tag)::value;
        float* dT   = wsf;
        float* BT   = dT + sz_dT;
        float* CT   = BT + sz_bc;
        float* hh   = CT + sz_bc;                       // hend -> hinit in place
        float* Ssm  = hh + (size_t)B_ * K_ * NCH * D_ * N_;
        k1_proj<<<B_ * K_ * (L_ / 64), 128, 0, stream>>>(qx, kv, xw, dtw, dtb, dT, BT, CT);
        k2_pass1<CHUNK><<<B_ * K_ * NCH, 128, 0, stream>>>(kv, dT, BT, alg, hh, Ssm);
        k25_chain<<<64, 256, 0, stream>>>(alg, Ssm, hh, NCH);
        k3_pass2<CHUNK><<<B_ * K_ * NCH, 128, 0, stream>>>(kv, dT, BT, CT, alg, Ds, hh, out);
    };

    const size_t need32 = (sz_dT + 2 * sz_bc + (size_t)B_*K_*128*D_*N_ + (size_t)B_*K_*128*D_) * sizeof(float);
    const size_t need128 = (sz_dT + 2 * sz_bc + (size_t)B_*K_*32*D_*N_ + (size_t)B_*K_*32*D_) * sizeof(float);

    if (ws_size >= need32)
        run(std::integral_constant<int, 32>{}, 128, (float*)d_ws);
    else if (ws_size >= need128)
        run(std::integral_constant<int, 128>{}, 32, (float*)d_ws);
}

// Round 3
// 83.874 us; speedup vs baseline: 2.6025x; 1.3343x over previous
//
#include <hip/hip_runtime.h>
#include <cmath>
#include <type_traits>

namespace {
constexpr int B_ = 2, K_ = 4, D_ = 128, L_ = 4096, N_ = 16, R_ = 8, C_ = 40;
constexpr float LOG2E = 1.44269504f;
}

#if __has_builtin(__builtin_amdgcn_exp2f)
#define FEXP2(x) __builtin_amdgcn_exp2f(x)
#else
#define FEXP2(x) exp2f(x)
#endif

// ---------------------------------------------------------------------------
// K1: projections only (rank-8 dts + B + C, all l-major). 512 threads = 8
// waves per (b,k,64-l tile). Waves 0-3: kv path, d-quarter each, 24 channels.
// Waves 4-7: q path, d-quarter each, 16 channels. LDS partial reduction.
// Delta expansion (R->D) moved into k2/k3.
// ---------------------------------------------------------------------------
__global__ __launch_bounds__(512, 4) void k1_proj(
    const float* __restrict__ qx, const float* __restrict__ kv,
    const float* __restrict__ xw,   // (K, 40, D)
    float* __restrict__ dtsT,       // (B,K,L,8)
    float* __restrict__ BT,         // (B,K,L,16)
    float* __restrict__ CT)         // (B,K,L,16)
{
    __shared__ float Wt[D_ * C_];          // [d][c]
    __shared__ float kvp_s[4][64][25];     // kv partials (24 ch + pad)
    __shared__ float qp_s[4][64][17];      // q  partials (16 ch + pad)

    const int tid = threadIdx.x;
    const int w = tid >> 6, lane = tid & 63;
    int blk = blockIdx.x;
    const int lt = blk & 63; blk >>= 6;            // L/64 = 64 tiles
    const int k = blk % K_; const int b = blk / K_;
    const int bk = b * K_ + k;
    const int l = lt * 64 + lane;

    for (int i = tid; i < C_ * D_; i += 512) {
        const int c = i >> 7, d = i & 127;
        Wt[d * C_ + c] = xw[(k * C_ + c) * D_ + d];
    }
    __syncthreads();

    if (w < 4) {
        float acc[24];
        #pragma unroll
        for (int c = 0; c < 24; ++c) acc[c] = 0.f;
        const float* src = kv + ((size_t)bk * D_ + w * 32) * L_ + l;
        #pragma unroll 8
        for (int dd = 0; dd < 32; ++dd) {
            const float v = src[(size_t)dd * L_];
            const float* wr = &Wt[(w * 32 + dd) * C_];
            #pragma unroll
            for (int c = 0; c < 24; ++c) acc[c] = fmaf(v, wr[c], acc[c]);
        }
        #pragma unroll
        for (int c = 0; c < 24; ++c) kvp_s[w][lane][c] = acc[c];
    } else {
        const int wq = w - 4;
        float acc[16];
        #pragma unroll
        for (int c = 0; c < 16; ++c) acc[c] = 0.f;
        const float* src = qx + ((size_t)bk * D_ + wq * 32) * L_ + l;
        #pragma unroll 8
        for (int dd = 0; dd < 32; ++dd) {
            const float v = src[(size_t)dd * L_];
            const float* wr = &Wt[(wq * 32 + dd) * C_ + 24];
            #pragma unroll
            for (int c = 0; c < 16; ++c) acc[c] = fmaf(v, wr[c], acc[c]);
        }
        #pragma unroll
        for (int c = 0; c < 16; ++c) qp_s[wq][lane][c] = acc[c];
    }
    __syncthreads();

    // dts: 64 l x 8 r, coalesced l-major write
    {
        const int l2 = tid >> 3, r = tid & 7;
        const float s = kvp_s[0][l2][r] + kvp_s[1][l2][r]
                      + kvp_s[2][l2][r] + kvp_s[3][l2][r];
        dtsT[((size_t)bk * L_ + lt * 64 + l2) * R_ + r] = s;
    }
    // B: 64 l x 16 ch
    for (int i = tid; i < 1024; i += 512) {
        const int l2 = i >> 4, c = i & 15;
        const float s = kvp_s[0][l2][8 + c] + kvp_s[1][l2][8 + c]
                      + kvp_s[2][l2][8 + c] + kvp_s[3][l2][8 + c];
        BT[((size_t)bk * L_ + lt * 64 + l2) * N_ + c] = s;
    }
    // C: 64 l x 16 ch
    for (int i = tid; i < 1024; i += 512) {
        const int l2 = i >> 4, c = i & 15;
        const float s = qp_s[0][l2][c] + qp_s[1][l2][c]
                      + qp_s[2][l2][c] + qp_s[3][l2][c];
        CT[((size_t)bk * L_ + lt * 64 + l2) * N_ + c] = s;
    }
}

// ---------------------------------------------------------------------------
// K2: pass 1. Thread = d (128/block), per (b,k,chunk). Delta computed in-
// register from broadcast dts (8 fma + softplus). 16 n-states in registers.
// ---------------------------------------------------------------------------
template<int CHUNK>
__global__ __launch_bounds__(128, 4) void k2_pass1(
    const float* __restrict__ kv, const float* __restrict__ dtsT,
    const float* __restrict__ BT, const float* __restrict__ alg,
    const float* __restrict__ dtw, const float* __restrict__ dtb,
    float* __restrict__ hend, float* __restrict__ Ssum)
{
    constexpr int NCH = L_ / CHUNK;
    constexpr int S = CHUNK + 1;
    constexpr int J = CHUNK / 4;
    __shared__ float u_s[D_ * S];
    __shared__ float dts_s[CHUNK * R_];
    __shared__ float B_s[CHUNK * N_];

    const int tid = threadIdx.x;
    const int d = tid;
    int blk = blockIdx.x;
    const int ch = blk % NCH; blk /= NCH;
    const int k = blk % K_; const int b = blk / K_;
    const int bk = b * K_ + k;

    for (int f = tid; f < D_ * J; f += 128) {
        const int d0 = f / J, j4 = (f % J) * 4;
        float4 v = *(const float4*)(kv + ((size_t)bk * D_ + d0) * L_ + ch * CHUNK + j4);
        float* p = &u_s[d0 * S + j4];
        p[0] = v.x; p[1] = v.y; p[2] = v.z; p[3] = v.w;
    }
    {
        const float* src = dtsT + ((size_t)bk * L_ + ch * CHUNK) * R_;
        for (int f = tid; f < CHUNK * 2; f += 128)
            *(float4*)&dts_s[4 * f] = *(const float4*)(src + 4 * f);
        const float* bsrc = BT + ((size_t)bk * L_ + ch * CHUNK) * N_;
        for (int f = tid; f < CHUNK * 4; f += 128)
            *(float4*)&B_s[4 * f] = *(const float4*)(bsrc + 4 * f);
    }
    __syncthreads();

    float dtwr[R_];
    {
        const float* p = dtw + ((size_t)k * D_ + d) * R_;
        *(float4*)&dtwr[0] = *(const float4*)p;
        *(float4*)&dtwr[4] = *(const float4*)(p + 4);
    }
    const float bias = dtb[k * D_ + d];
    float A2[N_];
    {
        const float* ap = alg + ((size_t)k * D_ + d) * N_;
        #pragma unroll
        for (int j = 0; j < 4; ++j) {
            float4 a = *(const float4*)(ap + 4 * j);
            A2[4*j]   = -__expf(a.x) * LOG2E; A2[4*j+1] = -__expf(a.y) * LOG2E;
            A2[4*j+2] = -__expf(a.z) * LOG2E; A2[4*j+3] = -__expf(a.w) * LOG2E;
        }
    }

    float h[N_];
    #pragma unroll
    for (int n = 0; n < N_; ++n) h[n] = 0.f;
    float sd = 0.f;

    #pragma unroll 4
    for (int l = 0; l < CHUNK; ++l) {
        float dv[R_];
        *(float4*)&dv[0] = *(const float4*)&dts_s[l * R_];
        *(float4*)&dv[4] = *(const float4*)&dts_s[l * R_ + 4];
        float s = bias;
        #pragma unroll
        for (int r = 0; r < R_; ++r) s = fmaf(dv[r], dtwr[r], s);
        const float e = FEXP2(s * LOG2E);
        const float dlt = (s > 15.f) ? s : __logf(1.f + e);
        sd += dlt;
        const float xb = dlt * u_s[d * S + l];
        float bv[N_];
        *(float4*)&bv[0]  = *(const float4*)&B_s[l * N_ + 0];
        *(float4*)&bv[4]  = *(const float4*)&B_s[l * N_ + 4];
        *(float4*)&bv[8]  = *(const float4*)&B_s[l * N_ + 8];
        *(float4*)&bv[12] = *(const float4*)&B_s[l * N_ + 12];
        #pragma unroll
        for (int n = 0; n < N_; ++n)
            h[n] = fmaf(FEXP2(dlt * A2[n]), h[n], xb * bv[n]);
    }

    float* hp = hend + (((size_t)bk * NCH + ch) * D_ + d) * N_;
    #pragma unroll
    for (int j = 0; j < 4; ++j) {
        float4 o; o.x = h[4*j]; o.y = h[4*j+1]; o.z = h[4*j+2]; o.w = h[4*j+3];
        *(float4*)(hp + 4 * j) = o;
    }
    Ssum[((size_t)bk * NCH + ch) * D_ + d] = sd;
}

// ---------------------------------------------------------------------------
// K2.5: serial chunk chain. hend -> hinit (separate buffers so the compiler
// can hoist loads past stores; exp is off the dependence chain).
// ---------------------------------------------------------------------------
__global__ __launch_bounds__(256, 2) void k25_chain(
    const float* __restrict__ alg, const float* __restrict__ Ssum,
    const float* __restrict__ hend, float* __restrict__ hinit, int NCH)
{
    const int tg = blockIdx.x * 256 + threadIdx.x;   // 16384 threads
    const int n = tg & 15;
    const int d = (tg >> 4) & 127;
    const int bk = tg >> 11;
    const int k = bk & 3;

    const float A2 = -__expf(alg[((size_t)k * D_ + d) * N_ + n]) * LOG2E;
    float h = 0.f;
    #pragma unroll 8
    for (int cc = 0; cc < NCH; ++cc) {
        const size_t si = ((size_t)bk * NCH + cc) * D_ + d;
        const float P = FEXP2(Ssum[si] * A2);
        const float he = hend[si * N_ + n];
        hinit[si * N_ + n] = h;
        h = fmaf(P, h, he);
    }
}

// ---------------------------------------------------------------------------
// K3: pass 2. Like K2 + C; y = sum_n h*C in registers, staged through LDS,
// flushed with +u*Ds coalesced.
// ---------------------------------------------------------------------------
template<int CHUNK>
__global__ __launch_bounds__(128, 4) void k3_pass2(
    const float* __restrict__ kv, const float* __restrict__ dtsT,
    const float* __restrict__ BT, const float* __restrict__ CT,
    const float* __restrict__ alg, const float* __restrict__ dtw,
    const float* __restrict__ dtb, const float* __restrict__ DsG,
    const float* __restrict__ hinit, float* __restrict__ out)
{
    constexpr int NCH = L_ / CHUNK;
    constexpr int S = CHUNK + 1;
    constexpr int J = CHUNK / 4;
    __shared__ float u_s[D_ * S];
    __shared__ float y_s[D_ * S];
    __shared__ float dts_s[CHUNK * R_];
    __shared__ float B_s[CHUNK * N_];
    __shared__ float C_s[CHUNK * N_];

    const int tid = threadIdx.x;
    const int d = tid;
    int blk = blockIdx.x;
    const int ch = blk % NCH; blk /= NCH;
    const int k = blk % K_; const int b = blk / K_;
    const int bk = b * K_ + k;

    for (int f = tid; f < D_ * J; f += 128) {
        const int d0 = f / J, j4 = (f % J) * 4;
        float4 v = *(const float4*)(kv + ((size_t)bk * D_ + d0) * L_ + ch * CHUNK + j4);
        float* p = &u_s[d0 * S + j4];
        p[0] = v.x; p[1] = v.y; p[2] = v.z; p[3] = v.w;
    }
    {
        const float* src = dtsT + ((size_t)bk * L_ + ch * CHUNK) * R_;
        for (int f = tid; f < CHUNK * 2; f += 128)
            *(float4*)&dts_s[4 * f] = *(const float4*)(src + 4 * f);
        const float* bsrc = BT + ((size_t)bk * L_ + ch * CHUNK) * N_;
        const float* csrc = CT + ((size_t)bk * L_ + ch * CHUNK) * N_;
        for (int f = tid; f < CHUNK * 4; f += 128) {
            *(float4*)&B_s[4 * f] = *(const float4*)(bsrc + 4 * f);
            *(float4*)&C_s[4 * f] = *(const float4*)(csrc + 4 * f);
        }
    }
    __syncthreads();

    float dtwr[R_];
    {
        const float* p = dtw + ((size_t)k * D_ + d) * R_;
        *(float4*)&dtwr[0] = *(const float4*)p;
        *(float4*)&dtwr[4] = *(const float4*)(p + 4);
    }
    const float bias = dtb[k * D_ + d];
    float A2[N_];
    {
        const float* ap = alg + ((size_t)k * D_ + d) * N_;
        #pragma unroll
        for (int j = 0; j < 4; ++j) {
            float4 a = *(const float4*)(ap + 4 * j);
            A2[4*j]   = -__expf(a.x) * LOG2E; A2[4*j+1] = -__expf(a.y) * LOG2E;
            A2[4*j+2] = -__expf(a.z) * LOG2E; A2[4*j+3] = -__expf(a.w) * LOG2E;
        }
    }

    float h[N_];
    {
        const float* hp = hinit + (((size_t)bk * NCH + ch) * D_ + d) * N_;
        #pragma unroll
        for (int j = 0; j < 4; ++j) {
            float4 v = *(const float4*)(hp + 4 * j);
            h[4*j] = v.x; h[4*j+1] = v.y; h[4*j+2] = v.z; h[4*j+3] = v.w;
        }
    }

    #pragma unroll 4
    for (int l = 0; l < CHUNK; ++l) {
        float dv[R_];
        *(float4*)&dv[0] = *(const float4*)&dts_s[l * R_];
        *(float4*)&dv[4] = *(const float4*)&dts_s[l * R_ + 4];
        float s = bias;
        #pragma unroll
        for (int r = 0; r < R_; ++r) s = fmaf(dv[r], dtwr[r], s);
        const float e = FEXP2(s * LOG2E);
        const float dlt = (s > 15.f) ? s : __logf(1.f + e);
        const float xb = dlt * u_s[d * S + l];
        float bv[N_], cv[N_];
        *(float4*)&bv[0]  = *(const float4*)&B_s[l * N_ + 0];
        *(float4*)&bv[4]  = *(const float4*)&B_s[l * N_ + 4];
        *(float4*)&bv[8]  = *(const float4*)&B_s[l * N_ + 8];
        *(float4*)&bv[12] = *(const float4*)&B_s[l * N_ + 12];
        *(float4*)&cv[0]  = *(const float4*)&C_s[l * N_ + 0];
        *(float4*)&cv[4]  = *(const float4*)&C_s[l * N_ + 4];
        *(float4*)&cv[8]  = *(const float4*)&C_s[l * N_ + 8];
        *(float4*)&cv[12] = *(const float4*)&C_s[l * N_ + 12];
        float p0 = 0.f, p1 = 0.f, p2 = 0.f, p3 = 0.f;
        #pragma unroll
        for (int n = 0; n < N_; ++n) {
            h[n] = fmaf(FEXP2(dlt * A2[n]), h[n], xb * bv[n]);
            if ((n & 3) == 0)      p0 = fmaf(h[n], cv[n], p0);
            else if ((n & 3) == 1) p1 = fmaf(h[n], cv[n], p1);
            else if ((n & 3) == 2) p2 = fmaf(h[n], cv[n], p2);
            else                   p3 = fmaf(h[n], cv[n], p3);
        }
        y_s[d * S + l] = (p0 + p1) + (p2 + p3);
    }
    __syncthreads();

    for (int f = tid; f < D_ * J; f += 128) {
        const int d0 = f / J, j4 = (f % J) * 4;
        const float Dv = DsG[k * D_ + d0];
        const float* yp = &y_s[d0 * S + j4];
        const float* up = &u_s[d0 * S + j4];
        float4 o;
        o.x = fmaf(up[0], Dv, yp[0]); o.y = fmaf(up[1], Dv, yp[1]);
        o.z = fmaf(up[2], Dv, yp[2]); o.w = fmaf(up[3], Dv, yp[3]);
        *(float4*)(out + ((size_t)bk * D_ + d0) * L_ + ch * CHUNK + j4) = o;
    }
}

extern "C" void kernel_launch(void* const* d_in, const int* in_sizes, int n_in,
                              void* d_out, int out_size, void* d_ws, size_t ws_size,
                              hipStream_t stream)
{
    const float* qx  = (const float*)d_in[0];
    const float* kv  = (const float*)d_in[1];
    const float* xw  = (const float*)d_in[2];
    const float* dtw = (const float*)d_in[3];
    const float* dtb = (const float*)d_in[4];
    const float* alg = (const float*)d_in[5];
    const float* Ds  = (const float*)d_in[6];
    float* out = (float*)d_out;

    const size_t sz_dts = (size_t)B_ * K_ * L_ * R_;   // 1,048,576
    const size_t sz_bc  = (size_t)B_ * K_ * L_ * N_;   //   524,288

    auto run = [&](auto chunk_tag) {
        constexpr int CHUNK = decltype(chunk_tag)::value;
        constexpr int NCH = L_ / CHUNK;
        const size_t sz_h = (size_t)B_ * K_ * NCH * D_ * N_;
        float* dts   = (float*)d_ws;
        float* BTp   = dts + sz_dts;
        float* CTp   = BTp + sz_bc;
        float* hend  = CTp + sz_bc;
        float* hinit = hend + sz_h;
        float* Ssm   = hinit + sz_h;
        k1_proj<<<B_ * K_ * (L_ / 64), 512, 0, stream>>>(qx, kv, xw, dts, BTp, CTp);
        k2_pass1<CHUNK><<<B_ * K_ * NCH, 128, 0, stream>>>(kv, dts, BTp, alg, dtw, dtb, hend, Ssm);
        k25_chain<<<64, 256, 0, stream>>>(alg, Ssm, hend, hinit, NCH);
        k3_pass2<CHUNK><<<B_ * K_ * NCH, 128, 0, stream>>>(kv, dts, BTp, CTp, alg, dtw, dtb, Ds, hinit, out);
    };

    auto need = [&](int NCH) {
        return (sz_dts + 2 * sz_bc
                + 2 * (size_t)B_ * K_ * NCH * D_ * N_
                + (size_t)B_ * K_ * NCH * D_) * sizeof(float);
    };

    if (ws_size >= need(128))      run(std::integral_constant<int, 32>{});
    else if (ws_size >= need(64))  run(std::integral_constant<int, 64>{});
    else if (ws_size >= need(32))  run(std::integral_constant<int, 128>{});
}